// Round 1
// baseline (481.414 us; speedup 1.0000x reference)
//
#include <hip/hip_runtime.h>

#define NN 100000   // N_SRC == N_DST
#define FD 64       // IN_SRC == IN_DST == OUT
#define NE 1250000  // E

// out[i,c] = bias[c] + sum_k x[i,k] * W[c,k]
// One wave per row; lane = output column c. Lane c keeps W row c in VGPRs.
// x row is read as wave-uniform float4 broadcast loads (16B/transaction).
__global__ __launch_bounds__(256) void linear64(
    const float* __restrict__ x, const float* __restrict__ W,
    const float* __restrict__ b, float* __restrict__ out, int n)
{
    const int lane  = threadIdx.x & 63;
    const int gwave = (int)((blockIdx.x * blockDim.x + threadIdx.x) >> 6);
    const int nwave = (int)((gridDim.x * blockDim.x) >> 6);

    // lane c holds W[c][0..63] in registers (16 KB total, one-time read via L2)
    float wreg[FD];
    #pragma unroll
    for (int k4 = 0; k4 < FD / 4; k4++) {
        const float4 wv = *(const float4*)(W + (size_t)lane * FD + k4 * 4);
        wreg[k4 * 4 + 0] = wv.x; wreg[k4 * 4 + 1] = wv.y;
        wreg[k4 * 4 + 2] = wv.z; wreg[k4 * 4 + 3] = wv.w;
    }
    const float bias = b ? b[lane] : 0.0f;

    for (int i = gwave; i < n; i += nwave) {
        float acc = bias;
        const float* xr = x + (size_t)i * FD;
        #pragma unroll
        for (int k4 = 0; k4 < FD / 4; k4++) {
            const float4 xv = *(const float4*)(xr + k4 * 4);  // wave-uniform broadcast
            acc = fmaf(xv.x, wreg[k4 * 4 + 0], acc);
            acc = fmaf(xv.y, wreg[k4 * 4 + 1], acc);
            acc = fmaf(xv.z, wreg[k4 * 4 + 2], acc);
            acc = fmaf(xv.w, wreg[k4 * 4 + 3], acc);
        }
        out[(size_t)i * FD + lane] = acc;  // coalesced 256B store
    }
}

// out[dst[e], c] += h[src[e], c] * w[e]  — one wave per edge, lane = column.
__global__ __launch_bounds__(256) void scatter_edges(
    const float* __restrict__ h, const int* __restrict__ eidx,
    const float* __restrict__ ew, float* __restrict__ out)
{
    const int lane  = threadIdx.x & 63;
    const int gwave = (int)((blockIdx.x * blockDim.x + threadIdx.x) >> 6);
    const int nwave = (int)((gridDim.x * blockDim.x) >> 6);
    const int* __restrict__ src = eidx;
    const int* __restrict__ dst = eidx + NE;

    for (int e = gwave; e < NE; e += nwave) {
        const int   s = src[e];                       // broadcast load
        const int   d = dst[e];
        const float w = ew[e];
        const float v = h[(size_t)s * FD + lane] * w; // coalesced 256B gather
        atomicAdd(out + (size_t)d * FD + lane, v);    // device-scope fp32 atomic
    }
}

// Fallback if d_ws can't hold h: recompute h row per edge (W_nei in VGPRs).
__global__ __launch_bounds__(256) void scatter_fused(
    const float* __restrict__ x_src, const float* __restrict__ Wn,
    const int* __restrict__ eidx, const float* __restrict__ ew,
    float* __restrict__ out)
{
    const int lane = threadIdx.x & 63;
    float wreg[FD];
    #pragma unroll
    for (int k4 = 0; k4 < FD / 4; k4++) {
        const float4 wv = *(const float4*)(Wn + (size_t)lane * FD + k4 * 4);
        wreg[k4 * 4 + 0] = wv.x; wreg[k4 * 4 + 1] = wv.y;
        wreg[k4 * 4 + 2] = wv.z; wreg[k4 * 4 + 3] = wv.w;
    }
    const int gwave = (int)((blockIdx.x * blockDim.x + threadIdx.x) >> 6);
    const int nwave = (int)((gridDim.x * blockDim.x) >> 6);
    const int* __restrict__ src = eidx;
    const int* __restrict__ dst = eidx + NE;

    for (int e = gwave; e < NE; e += nwave) {
        const int   s = src[e];
        const int   d = dst[e];
        const float w = ew[e];
        float acc = 0.0f;
        const float* xr = x_src + (size_t)s * FD;
        #pragma unroll
        for (int k4 = 0; k4 < FD / 4; k4++) {
            const float4 xv = *(const float4*)(xr + k4 * 4);
            acc = fmaf(xv.x, wreg[k4 * 4 + 0], acc);
            acc = fmaf(xv.y, wreg[k4 * 4 + 1], acc);
            acc = fmaf(xv.z, wreg[k4 * 4 + 2], acc);
            acc = fmaf(xv.w, wreg[k4 * 4 + 3], acc);
        }
        atomicAdd(out + (size_t)d * FD + lane, acc * w);
    }
}

extern "C" void kernel_launch(void* const* d_in, const int* in_sizes, int n_in,
                              void* d_out, int out_size, void* d_ws, size_t ws_size,
                              hipStream_t stream)
{
    const float* x_src  = (const float*)d_in[0];
    const float* x_dst  = (const float*)d_in[1];
    const int*   eidx   = (const int*)  d_in[2];  // [2, E] row-major: src then dst
    const float* ew     = (const float*)d_in[3];
    const float* W_nei  = (const float*)d_in[4];
    const float* W_self = (const float*)d_in[5];
    const float* b_self = (const float*)d_in[6];
    float* out = (float*)d_out;

    // 1) self term (fully overwrites d_out — no pre-zero needed)
    linear64<<<1024, 256, 0, stream>>>(x_dst, W_self, b_self, out, NN);

    const size_t h_bytes = (size_t)NN * FD * sizeof(float);
    if (ws_size >= h_bytes) {
        float* h = (float*)d_ws;
        // 2) neighbor transform into workspace
        linear64<<<1024, 256, 0, stream>>>(x_src, W_nei, nullptr, h, NN);
        // 3) edge scatter
        scatter_edges<<<2048, 256, 0, stream>>>(h, eidx, ew, out);
    } else {
        scatter_fused<<<2048, 256, 0, stream>>>(x_src, W_nei, eidx, ew, out);
    }
}